// Round 7
// baseline (862.045 us; speedup 1.0000x reference)
//
#include <hip/hip_runtime.h>

typedef _Float16 f16;
typedef _Float16 f16x8 __attribute__((ext_vector_type(8)));
typedef float floatx4 __attribute__((ext_vector_type(4)));

__device__ __forceinline__ float ftanh(float x) {
  float ax = __builtin_fabsf(x);
  float e  = __expf(-2.0f * ax);
  float t  = (1.0f - e) * __builtin_amdgcn_rcpf(1.0f + e);
  return x < 0.0f ? -t : t;
}

// async global->LDS, 16B/lane; LDS base wave-uniform, HW scatters lane i to base+i*16.
__device__ __forceinline__ void gll16(const f16* g, f16* l) {
  __builtin_amdgcn_global_load_lds(
      (const __attribute__((address_space(1))) void*)g,
      (__attribute__((address_space(3))) void*)l, 16, 0, 0);
}

// 128 x (FJ*32) tile GEMM step, 256 threads / 4 waves, 2x2 wave grid (r3 shape —
// best measured; r5 8-wave null, r6 3-blk/CU regression).
// ROUND 7: W-operand bypasses LDS. r5/r6 A/B results say the rnn span is bound
// by LDS staging traffic (~2.5 MB/CU/wv ≈ 11 us), not wave parallelism. W [n][k]
// k-contiguous lets each lane load its MFMA B-fragment (16 B) straight from L2:
// a wave consumes 16 full 64-B lines per fragment load — line-efficient. W frags
// are double-buffered in registers across K-steps (prefetch issued right after
// the previous barrier -> ~1 full step of latency cover). Removes W's LDS write
// AND its 2x-duplicated LDS read; LDS now stages A only (swizzled gll16 dbuf,
// verified r1-r3). K is a template param so the K-loop fully unrolls and all
// double-buffer indices are compile-time (no scratch).
template<int FJ, int K>
__device__ __forceinline__ void tile_gemm(
    const f16* __restrict__ A0, int ldA0,   // k in [0,512)
    const f16* __restrict__ A1, int ldA1,   // k in [512,K), col index k-512
    const f16* __restrict__ WT,             // [512][K] k-contiguous
    const float* __restrict__ bias,
    f16* __restrict__ outp, int bm, int bn, f16* sm)
{
  const int tid  = threadIdx.x;
  const int w    = tid >> 6;
  const int lane = tid & 63;
  const int lm   = lane & 15;
  const int quad = lane >> 4;
  const int wm   = (w >> 1) * 64;
  const int wn   = (w & 1) * (FJ * 16);
  const int srow8 = lane >> 3;
  const int scol  = ((lane & 7) ^ srow8) * 8;   // pre-swizzled global source col (A)
  const int lmx   = lane & 7;
  constexpr int SB = 8192;                      // f16 per A buffer (128 x 64)
  constexpr int NS = K / 64;

  floatx4 acc[4][FJ];
  #pragma unroll
  for (int i = 0; i < 4; ++i)
    #pragma unroll
    for (int j = 0; j < FJ; ++j)
      acc[i][j] = (floatx4){0.f, 0.f, 0.f, 0.f};

  // per-lane W fragment base: row bn+wn+fj*16+lm, col quad*8
  const f16* wp = WT + (size_t)(bn + wn + lm) * K + quad * 8;

  f16x8 bfr[2][FJ][2];
  #pragma unroll
  for (int fj = 0; fj < FJ; ++fj) {
    bfr[0][fj][0] = *(const f16x8*)(wp + (size_t)fj * 16 * K);
    bfr[0][fj][1] = *(const f16x8*)(wp + (size_t)fj * 16 * K + 32);
  }
  #pragma unroll
  for (int i = 0; i < 4; ++i) {               // stage A(0)
    int r = (w * 4 + i) * 8 + srow8;
    gll16(A0 + (size_t)(bm + r) * ldA0 + scol, sm + (w * 4 + i) * 512);
  }
  __syncthreads();                            // drains stage(0) + W(0)

  #pragma unroll
  for (int s = 0; s < NS; ++s) {
    if (s + 1 < NS) {
      const int k0n = (s + 1) * 64;
      // W(s+1) -> regs first (latency-critical), then A(s+1) -> LDS
      #pragma unroll
      for (int fj = 0; fj < FJ; ++fj) {
        bfr[(s + 1) & 1][fj][0] = *(const f16x8*)(wp + (size_t)fj * 16 * K + k0n);
        bfr[(s + 1) & 1][fj][1] = *(const f16x8*)(wp + (size_t)fj * 16 * K + k0n + 32);
      }
      const f16* Asrc = (k0n < 512) ? (A0 + k0n) : (A1 + (k0n - 512));
      const int  ld   = (k0n < 512) ? ldA0 : ldA1;
      f16* As1 = sm + ((s + 1) & 1) * SB;
      #pragma unroll
      for (int i = 0; i < 4; ++i) {
        int r = (w * 4 + i) * 8 + srow8;
        gll16(Asrc + (size_t)(bm + r) * ld + scol, As1 + (w * 4 + i) * 512);
      }
    }
    const f16* As0 = sm + (s & 1) * SB;
    #pragma unroll
    for (int kk = 0; kk < 64; kk += 32) {
      const int sw = (((kk >> 3) + quad) ^ lmx) << 3;  // swizzled 16B-slot (A)
      f16x8 a[4];
      #pragma unroll
      for (int fi = 0; fi < 4; ++fi)
        a[fi] = *(const f16x8*)&As0[(size_t)(wm + fi * 16 + lm) * 64 + sw];
      #pragma unroll
      for (int fi = 0; fi < 4; ++fi)
        #pragma unroll
        for (int fj = 0; fj < FJ; ++fj)
          acc[fi][fj] = __builtin_amdgcn_mfma_f32_16x16x32_f16(
              a[fi], bfr[s & 1][fj][kk >> 5], acc[fi][fj], 0, 0, 0);
    }
    __syncthreads();   // waits A(s+1)/W(s+1) (vmcnt0) + releases A buf (s&1)
  }

  // epilogue: C/D layout col=lane&15, row=quad*4+reg [m89/m91] -> LDS transpose
  constexpr int ES = FJ * 32 + 8;
  #pragma unroll
  for (int fi = 0; fi < 4; ++fi)
    #pragma unroll
    for (int fj = 0; fj < FJ; ++fj) {
      int col = wn + fj * 16 + lm;
      #pragma unroll
      for (int r = 0; r < 4; ++r) {
        int row = wm + fi * 16 + quad * 4 + r;
        sm[row * ES + col] = (f16)acc[fi][fj][r];
      }
    }
  __syncthreads();
  constexpr int TPR = (FJ * 32) / 8;     // threads per row
  constexpr int RPP = 256 / TPR;         // rows per pass
  #pragma unroll
  for (int p = 0; p < 128 / RPP; ++p) {
    int row = p * RPP + tid / TPR;
    int c8  = (tid % TPR) * 8;
    f16x8 ve = *(const f16x8*)&sm[row * ES + c8];
    floatx4 bv0 = *(const floatx4*)&bias[bn + c8];
    floatx4 bv1 = *(const floatx4*)&bias[bn + c8 + 4];
    union { f16 e[8]; f16x8 v; } o;
    #pragma unroll
    for (int j = 0; j < 4; ++j) o.e[j]     = (f16)ftanh((float)ve[j]     + bv0[j]);
    #pragma unroll
    for (int j = 0; j < 4; ++j) o.e[4 + j] = (f16)ftanh((float)ve[4 + j] + bv1[j]);
    *(f16x8*)(outp + (size_t)(bm + row) * 512 + bn + c8) = o.v;
  }
}

// One anti-diagonal wavefront: 512 blocks x 256 threads (r3 shape), 2 blocks/CU
// (one z0 + one z1/z2 per CU via in-order round-robin). slab<->XCD fixed across
// layers/wavefronts so H tiles stay in the home XCD's L2. Round-1 lesson: no
// software grid barriers (~25 us/barrier worse). Round-6 lesson: bn=64 for
// z1/z2 doubles W traffic — keep FJ=4 there.
__global__ __launch_bounds__(256, 2)
void rnn_step(int wv, const f16* __restrict__ xh,
              const f16* __restrict__ W0T, const f16* __restrict__ W1T,
              const f16* __restrict__ W2T,
              const float* __restrict__ bcomb, const float* __restrict__ b1,
              const float* __restrict__ b2,
              const f16* __restrict__ H0c, f16* __restrict__ H0n,
              const f16* __restrict__ H1c, f16* __restrict__ H1n,
              const f16* __restrict__ H2c, f16* __restrict__ H2n)
{
  __shared__ f16 sm[17408];   // 34816 B: A dbuf 2x16KB / epi 128x136
  const int b   = blockIdx.x;
  const int xcd = b & 7;
  const int r   = b >> 3;     // 0..63

  if (r < 32) {               // z0: 256 blocks, tile 128x64, K=832
    if (wv > 19) return;
    const int slab = xcd * 4 + (r & 3);
    const int bn   = (r >> 2) * 64;
    tile_gemm<2, 832>(H0c, 512, xh + (size_t)wv * 320, 6400, W0T, bcomb,
                      H0n, slab * 128, bn, sm);
  } else if (r < 48) {        // z1: 128 blocks, tile 128x128, K=1024
    if (wv < 1 || wv > 20) return;
    const int rr   = r - 32;
    const int slab = xcd * 4 + (rr & 3);
    const int bn   = (rr >> 2) * 128;
    tile_gemm<4, 1024>(H0c, 512, H1c, 512, W1T, b1, H1n, slab * 128, bn, sm);
  } else {                    // z2: 128 blocks, tile 128x128, K=1024
    if (wv < 2) return;
    const int rr   = r - 48;
    const int slab = xcd * 4 + (rr & 3);
    const int bn   = (rr >> 2) * 128;
    tile_gemm<4, 1024>(H1c, 512, H2c, 512, W2T, b2, H2n, slab * 128, bn, sm);
  }
}

// ---------------------------------------------------------------------------
// Prep, two dispatches (round 4+) for rocprof attribution:
//   prep_x : x fp32 -> xh f16 (zero-padded to 320), 8 chunks/thread
//   prep_w : Wce fold + bcomb (8-block split-K) + weight transposes (f16x8
//            stores) + H zero-init
// ---------------------------------------------------------------------------
#define PX_N 1600

__global__ __launch_bounds__(256)
void prep_x(const float* __restrict__ x, f16* __restrict__ xh)
{
  const int NTH = PX_N * 256;
  const int g = blockIdx.x * 256 + threadIdx.x;
  floatx4 va[8], vb[8];
  int rw[8], cc[8];
  const floatx4 z4 = {0.f, 0.f, 0.f, 0.f};
  #pragma unroll
  for (int s = 0; s < 8; ++s) {
    int U = g + s * NTH;
    int row = U / 40;
    int c   = (U - row * 40) * 8;
    rw[s] = row; cc[s] = c;
    const float* src = x + (size_t)row * 300 + c;
    va[s] = (c + 4 <= 300) ? *(const floatx4*)src : z4;        // c=296: 4 real
    vb[s] = (c + 8 <= 300) ? *(const floatx4*)(src + 4) : z4;  // c>=296: pad
  }
  #pragma unroll
  for (int s = 0; s < 8; ++s) {
    union { f16 e[8]; f16x8 v; } t;
    #pragma unroll
    for (int j = 0; j < 4; ++j) { t.e[j] = (f16)va[s][j]; t.e[4 + j] = (f16)vb[s][j]; }
    *(f16x8*)(xh + (size_t)rw[s] * 320 + cc[s]) = t.v;
  }
}

#define PW_WCE 2560
#define PW_BC  2568
#define PW_WT  3208
#define PW_Z   6280

__global__ __launch_bounds__(256)
void prep_w(const float* __restrict__ W_emb, const float* __restrict__ b_emb,
            const float* __restrict__ wx0, const float* __restrict__ wh0,
            const float* __restrict__ b0,
            const float* __restrict__ wx1, const float* __restrict__ wh1,
            const float* __restrict__ wx2, const float* __restrict__ wh2,
            f16* __restrict__ W0T, f16* __restrict__ W1T, f16* __restrict__ W2T,
            float* __restrict__ bcomb,
            f16* __restrict__ H0a, f16* __restrict__ H1b, f16* __restrict__ H2a)
{
  __shared__ float red[256];
  const int b   = blockIdx.x;
  const int tid = threadIdx.x;

  if (b < PW_WCE) {
    // Wce[k][n] = sum_j W_emb[k][j]*wx0[j][n]; 64 outputs x 4 j-chunks per block
    int oidx  = b * 64 + (tid & 63);      // 0..163839
    int chunk = tid >> 6;                  // 0..3
    int n = oidx & 511, k = oidx >> 9;     // k 0..319
    float s = 0.f;
    if (k < 300) {
      const float* we = W_emb + k * 512 + chunk * 128;
      const float* wx = wx0 + (size_t)(chunk * 128) * 512 + n;
      #pragma unroll 4
      for (int j = 0; j < 128; ++j)
        s = __builtin_fmaf(we[j], wx[(size_t)j * 512], s);
    }
    red[tid] = s;
    __syncthreads();
    if (chunk == 0)
      W0T[(size_t)n * 832 + 512 + k] =
          (f16)(red[tid] + red[tid + 64] + red[tid + 128] + red[tid + 192]);
  } else if (b < PW_BC) {
    // bcomb[n] = b0[n] + sum_j b_emb[j]*wx0[j][n]; 8 blocks, split-K x4
    int n     = (b - PW_WCE) * 64 + (tid & 63);
    int chunk = tid >> 6;
    float s = 0.f;
    const float* be = b_emb + chunk * 128;
    const float* wx = wx0 + (size_t)(chunk * 128) * 512 + n;
    #pragma unroll 4
    for (int j = 0; j < 128; ++j)
      s = __builtin_fmaf(be[j], wx[(size_t)j * 512], s);
    red[tid] = s;
    __syncthreads();
    if (chunk == 0)
      bcomb[n] = b0[n] + red[tid] + red[tid + 64] + red[tid + 128] + red[tid + 192];
  } else if (b < PW_WT) {
    // transposes, f16x8 stores: 640*256 = 163,840 k8-chunks
    int id = (b - PW_BC) * 256 + tid;
    if (id < 32768) {                        // W0T k<512 from wh0
      int n = id & 511, k8 = id >> 9;        // k8 0..63
      union { f16 e[8]; f16x8 v; } t;
      #pragma unroll
      for (int j = 0; j < 8; ++j) t.e[j] = (f16)wh0[(size_t)(k8 * 8 + j) * 512 + n];
      *(f16x8*)&W0T[(size_t)n * 832 + k8 * 8] = t.v;
    } else if (id < 98304) {                 // W1T from wx1/wh1
      int i2 = id - 32768;
      int n = i2 & 511, k8 = i2 >> 9;        // k8 0..127; chunks don't straddle 512
      union { f16 e[8]; f16x8 v; } t;
      const float* src = (k8 < 64) ? (wx1 + (size_t)(k8 * 8) * 512 + n)
                                   : (wh1 + (size_t)((k8 - 64) * 8) * 512 + n);
      #pragma unroll
      for (int j = 0; j < 8; ++j) t.e[j] = (f16)src[(size_t)j * 512];
      *(f16x8*)&W1T[(size_t)n * 1024 + k8 * 8] = t.v;
    } else {                                 // W2T from wx2/wh2
      int i2 = id - 98304;
      int n = i2 & 511, k8 = i2 >> 9;
      union { f16 e[8]; f16x8 v; } t;
      const float* src = (k8 < 64) ? (wx2 + (size_t)(k8 * 8) * 512 + n)
                                   : (wh2 + (size_t)((k8 - 64) * 8) * 512 + n);
      #pragma unroll
      for (int j = 0; j < 8; ++j) t.e[j] = (f16)src[(size_t)j * 512];
      *(f16x8*)&W2T[(size_t)n * 1024 + k8 * 8] = t.v;
    }
  } else {
    // zero-init h(-1): H0a, H1b, H2a — 3072*256 = 786,432 f16x8 chunks
    int id = (b - PW_WT) * 256 + tid;
    f16x8 z8 = {};
    f16* dst = (id < 262144) ? H0a : (id < 524288) ? H1b : H2a;
    *(f16x8*)(dst + (size_t)(id & 262143) * 8) = z8;
  }
}

// out[4096,10] = h2[4096,512](f16) @ W_fc[512,10] + b_fc; W_fc staged in LDS
__global__ void fc_kernel(const f16* __restrict__ h2,
                          const float* __restrict__ Wfc, const float* __restrict__ bfc,
                          float* __restrict__ out)
{
  __shared__ float wf[5120];
  __shared__ float bf[16];
  const int tid = threadIdx.x;
  for (int i = tid; i < 5120; i += 256) wf[i] = Wfc[i];
  if (tid < 10) bf[tid] = bfc[tid];
  __syncthreads();
  int id = blockIdx.x * 256 + tid;           // 40960 exactly
  int row = id / 10;
  int c = id - row * 10;
  float s = bf[c];
  const f16* hr = h2 + (size_t)row * 512;
  for (int k8 = 0; k8 < 64; ++k8) {
    f16x8 h8 = *(const f16x8*)(hr + k8 * 8);
    #pragma unroll
    for (int j = 0; j < 8; ++j)
      s = __builtin_fmaf((float)h8[j], wf[(k8 * 8 + j) * 10 + c], s);
  }
  out[id] = s;
}

extern "C" void kernel_launch(void* const* d_in, const int* in_sizes, int n_in,
                              void* d_out, int out_size, void* d_ws, size_t ws_size,
                              hipStream_t stream)
{
  (void)in_sizes; (void)n_in; (void)out_size; (void)ws_size;
  const float* x     = (const float*)d_in[0];
  const float* W_emb = (const float*)d_in[1];
  const float* b_emb = (const float*)d_in[2];
  const float* wx0   = (const float*)d_in[3];
  const float* wh0   = (const float*)d_in[4];
  const float* b0    = (const float*)d_in[5];
  const float* wx1   = (const float*)d_in[6];
  const float* wh1   = (const float*)d_in[7];
  const float* b1    = (const float*)d_in[8];
  const float* wx2   = (const float*)d_in[9];
  const float* wh2   = (const float*)d_in[10];
  const float* b2    = (const float*)d_in[11];
  const float* W_fc  = (const float*)d_in[12];
  const float* b_fc  = (const float*)d_in[13];
  float* out = (float*)d_out;

  char* ws = (char*)d_ws;
  size_t off = 0;
  auto alloc = [&](size_t bytes) -> void* {
    void* p = ws + off;
    off = (off + bytes + 255) & ~(size_t)255;
    return p;
  };
  f16*   xh    = (f16*)alloc((size_t)81920 * 320 * 2);   // 52.4 MB
  f16*   W0T   = (f16*)alloc((size_t)512 * 832 * 2);
  f16*   W1T   = (f16*)alloc((size_t)512 * 1024 * 2);
  f16*   W2T   = (f16*)alloc((size_t)512 * 1024 * 2);
  float* bcomb = (float*)alloc(512 * 4);
  f16*   H0a   = (f16*)alloc((size_t)4096 * 512 * 2);
  f16*   H0b   = (f16*)alloc((size_t)4096 * 512 * 2);
  f16*   H1a   = (f16*)alloc((size_t)4096 * 512 * 2);
  f16*   H1b   = (f16*)alloc((size_t)4096 * 512 * 2);
  f16*   H2a   = (f16*)alloc((size_t)4096 * 512 * 2);
  f16*   H2b   = (f16*)alloc((size_t)4096 * 512 * 2);

  // prep: two dispatches (xh conversion | weights/bias/zero-init)
  prep_x<<<PX_N, 256, 0, stream>>>(x, xh);
  prep_w<<<PW_Z, 256, 0, stream>>>(W_emb, b_emb, wx0, wh0, b0,
                                   wx1, wh1, wx2, wh2,
                                   W0T, W1T, W2T, bcomb, H0a, H1b, H2a);

  // 22 anti-diagonal wavefronts: z0(t=wv), z1(t=wv-1), z2(t=wv-2)
  for (int wv = 0; wv < 22; ++wv) {
    const int cur = wv & 1;
    f16* H0c = cur ? H0b : H0a;  f16* H0n = cur ? H0a : H0b;
    f16* H1c = cur ? H1b : H1a;  f16* H1n = cur ? H1a : H1b;
    f16* H2c = cur ? H2b : H2a;  f16* H2n = cur ? H2a : H2b;
    rnn_step<<<512, 256, 0, stream>>>(wv, xh, W0T, W1T, W2T, bcomb, b1, b2,
                                      H0c, H0n, H1c, H1n, H2c, H2n);
  }

  // h2(19) written at wv=21 into H2n(cur=1) = H2a
  fc_kernel<<<160, 256, 0, stream>>>(H2a, W_fc, b_fc, out);
}

// Round 8
// 553.042 us; speedup vs baseline: 1.5587x; 1.5587x over previous
//
#include <hip/hip_runtime.h>

typedef _Float16 f16;
typedef _Float16 f16x8 __attribute__((ext_vector_type(8)));
typedef float floatx4 __attribute__((ext_vector_type(4)));

__device__ __forceinline__ float ftanh(float x) {
  float ax = __builtin_fabsf(x);
  float e  = __expf(-2.0f * ax);
  float t  = (1.0f - e) * __builtin_amdgcn_rcpf(1.0f + e);
  return x < 0.0f ? -t : t;
}

// async global->LDS, 16B/lane; LDS base wave-uniform, HW scatters lane i to base+i*16.
__device__ __forceinline__ void gll16(const f16* g, f16* l) {
  __builtin_amdgcn_global_load_lds(
      (const __attribute__((address_space(1))) void*)g,
      (__attribute__((address_space(3))) void*)l, 16, 0, 0);
}

// 128 x (FJ*32) tile GEMM step, 256 threads / 4 waves, 2x2 wave grid — the r3
// structure (best measured: 592 us). r5 (8 waves): null; r6 (3 blk/CU): -34;
// r7 (W in regs): -270. This decomposition is a sharp local optimum; only
// additive tweaks below.
// T2 XOR-swizzle (verified r1-r3: conflicts ~3%): linear LDS dest + inverse-
// swizzled GLOBAL source col + swizzled ds_read slot. Double-buffered staging,
// one barrier per K-step, prefetch issued before compute (verified r3: -4.3us/wv).
// ROUND 8: s_setprio(1) around the MFMA cluster (T5) — each CU holds one z0 and
// one z1/z2 block at different phases, so the scheduler has roles to arbitrate.
template<int FJ>
__device__ __forceinline__ void tile_gemm(
    const f16* __restrict__ A0, int ldA0,   // k in [0,512)
    const f16* __restrict__ A1, int ldA1,   // k in [512,K), col index k-512
    int K, const f16* __restrict__ WT,
    const float* __restrict__ bias,
    f16* __restrict__ outp, int bm, int bn, f16* sm)
{
  const int tid  = threadIdx.x;
  const int w    = tid >> 6;
  const int lane = tid & 63;
  const int lm   = lane & 15;
  const int quad = lane >> 4;
  const int wm   = (w >> 1) * 64;
  const int wn   = (w & 1) * (FJ * 16);
  const int srow8 = lane >> 3;
  const int scol  = ((lane & 7) ^ srow8) * 8;   // pre-swizzled global source col
  const int lmx   = lane & 7;
  constexpr int SB = 8192 + FJ * 2048;          // f16 units per LDS buffer (A+W)

  floatx4 acc[4][FJ];
  #pragma unroll
  for (int i = 0; i < 4; ++i)
    #pragma unroll
    for (int j = 0; j < FJ; ++j)
      acc[i][j] = (floatx4){0.f, 0.f, 0.f, 0.f};

  auto stage = [&](int buf, int k0) {
    const f16* Asrc = (k0 < 512) ? (A0 + k0) : (A1 + (k0 - 512));
    const int  ld   = (k0 < 512) ? ldA0 : ldA1;
    f16* As0 = sm + buf * SB;
    f16* Ws0 = As0 + 8192;
    #pragma unroll
    for (int i = 0; i < 4; ++i) {
      int r = (w * 4 + i) * 8 + srow8;
      gll16(Asrc + (size_t)(bm + r) * ld + scol, As0 + (w * 4 + i) * 512);
    }
    #pragma unroll
    for (int i = 0; i < FJ; ++i) {
      int r = (w * FJ + i) * 8 + srow8;
      gll16(WT + (size_t)(bn + r) * K + k0 + scol, Ws0 + (w * FJ + i) * 512);
    }
  };

  const int NS = K >> 6;
  stage(0, 0);
  __syncthreads();                      // drains stage(0): implicit vmcnt(0)
  for (int s = 0; s < NS; ++s) {
    if (s + 1 < NS) stage((s + 1) & 1, (s + 1) << 6);   // prefetch next tile
    const f16* As0 = sm + (s & 1) * SB;
    const f16* Ws0 = As0 + 8192;
    #pragma unroll
    for (int kk = 0; kk < 64; kk += 32) {
      const int sw = (((kk >> 3) + quad) ^ lmx) << 3;  // swizzled 16B-slot, f16 units
      f16x8 a[4], bfr[FJ];
      #pragma unroll
      for (int fi = 0; fi < 4; ++fi)
        a[fi] = *(const f16x8*)&As0[(size_t)(wm + fi * 16 + lm) * 64 + sw];
      #pragma unroll
      for (int fj = 0; fj < FJ; ++fj)
        bfr[fj] = *(const f16x8*)&Ws0[(size_t)(wn + fj * 16 + lm) * 64 + sw];
      __builtin_amdgcn_s_setprio(1);
      #pragma unroll
      for (int fi = 0; fi < 4; ++fi)
        #pragma unroll
        for (int fj = 0; fj < FJ; ++fj)
          acc[fi][fj] = __builtin_amdgcn_mfma_f32_16x16x32_f16(a[fi], bfr[fj], acc[fi][fj], 0, 0, 0);
      __builtin_amdgcn_s_setprio(0);
    }
    __syncthreads();   // waits stage(s+1) (vmcnt0) + releases buf(s&1) for reuse
  }

  // epilogue: C/D layout col=lane&15, row=quad*4+reg [m89/m91] -> LDS transpose
  constexpr int ES = FJ * 32 + 8;
  #pragma unroll
  for (int fi = 0; fi < 4; ++fi)
    #pragma unroll
    for (int fj = 0; fj < FJ; ++fj) {
      int col = wn + fj * 16 + lm;
      #pragma unroll
      for (int r = 0; r < 4; ++r) {
        int row = wm + fi * 16 + quad * 4 + r;
        sm[row * ES + col] = (f16)acc[fi][fj][r];
      }
    }
  __syncthreads();
  constexpr int TPR = (FJ * 32) / 8;     // threads per row
  constexpr int RPP = 256 / TPR;         // rows per pass
  #pragma unroll
  for (int p = 0; p < 128 / RPP; ++p) {
    int row = p * RPP + tid / TPR;
    int c8  = (tid % TPR) * 8;
    f16x8 ve = *(const f16x8*)&sm[row * ES + c8];
    floatx4 bv0 = *(const floatx4*)&bias[bn + c8];
    floatx4 bv1 = *(const floatx4*)&bias[bn + c8 + 4];
    union { f16 e[8]; f16x8 v; } o;
    #pragma unroll
    for (int j = 0; j < 4; ++j) o.e[j]     = (f16)ftanh((float)ve[j]     + bv0[j]);
    #pragma unroll
    for (int j = 0; j < 4; ++j) o.e[4 + j] = (f16)ftanh((float)ve[4 + j] + bv1[j]);
    *(f16x8*)(outp + (size_t)(bm + row) * 512 + bn + c8) = o.v;
  }
}

// One anti-diagonal wavefront: 512 blocks, 2/CU, balanced (one z0 + one z1/z2
// per CU via in-order round-robin). slab<->XCD fixed across layers/wavefronts
// so H tiles stay in the home XCD's L2. Round-1 lesson: no software grid
// barriers (~25 us/barrier worse than HW dispatch).
__global__ __launch_bounds__(256, 2)
void rnn_step(int wv, const f16* __restrict__ xh,
              const f16* __restrict__ W0T, const f16* __restrict__ W1T,
              const f16* __restrict__ W2T,
              const float* __restrict__ bcomb, const float* __restrict__ b1,
              const float* __restrict__ b2,
              const f16* __restrict__ H0c, f16* __restrict__ H0n,
              const f16* __restrict__ H1c, f16* __restrict__ H1n,
              const f16* __restrict__ H2c, f16* __restrict__ H2n)
{
  __shared__ f16 sm[32768];   // 64 KB: dbuf staging 2x32KB (FJ=4) / epi 128x136
  const int b   = blockIdx.x;
  const int xcd = b & 7;
  const int r   = b >> 3;     // 0..63

  if (r < 32) {               // z0: 256 blocks, tile 128x64, K=832
    if (wv > 19) return;
    const int slab = xcd * 4 + (r & 3);
    const int bn   = (r >> 2) * 64;
    tile_gemm<2>(H0c, 512, xh + (size_t)wv * 320, 6400, 832, W0T, bcomb,
                 H0n, slab * 128, bn, sm);
  } else if (r < 48) {        // z1: 128 blocks, tile 128x128, K=1024
    if (wv < 1 || wv > 20) return;
    const int rr   = r - 32;
    const int slab = xcd * 4 + (rr & 3);
    const int bn   = (rr >> 2) * 128;
    tile_gemm<4>(H0c, 512, H1c, 512, 1024, W1T, b1, H1n, slab * 128, bn, sm);
  } else {                    // z2: 128 blocks, tile 128x128, K=1024
    if (wv < 2) return;
    const int rr   = r - 48;
    const int slab = xcd * 4 + (rr & 3);
    const int bn   = (rr >> 2) * 128;
    tile_gemm<4>(H1c, 512, H2c, 512, 1024, W2T, b2, H2n, slab * 128, bn, sm);
  }
}

// ---------------------------------------------------------------------------
// Prep, two dispatches for attribution:
//   prep_x : x fp32 -> xh f16 (zero-padded to 320), 8 chunks/thread
//   prep_w : Wce (ROUND 8: 640-block LDS-tiled — old form read a 131 KB wx0
//            panel per 64 outputs = 335 MB L2 traffic for a 167 MF GEMM; now
//            16kx16n tiles staged in LDS, ~40 MB total) + bcomb split-K +
//            weight transposes (f16x8 stores) + H zero-init
// ---------------------------------------------------------------------------
#define PX_N 1600

__global__ __launch_bounds__(256)
void prep_x(const float* __restrict__ x, f16* __restrict__ xh)
{
  const int NTH = PX_N * 256;
  const int g = blockIdx.x * 256 + threadIdx.x;
  floatx4 va[8], vb[8];
  int rw[8], cc[8];
  const floatx4 z4 = {0.f, 0.f, 0.f, 0.f};
  #pragma unroll
  for (int s = 0; s < 8; ++s) {
    int U = g + s * NTH;
    int row = U / 40;
    int c   = (U - row * 40) * 8;
    rw[s] = row; cc[s] = c;
    const float* src = x + (size_t)row * 300 + c;
    va[s] = (c + 4 <= 300) ? *(const floatx4*)src : z4;        // c=296: 4 real
    vb[s] = (c + 8 <= 300) ? *(const floatx4*)(src + 4) : z4;  // c>=296: pad
  }
  #pragma unroll
  for (int s = 0; s < 8; ++s) {
    union { f16 e[8]; f16x8 v; } t;
    #pragma unroll
    for (int j = 0; j < 4; ++j) { t.e[j] = (f16)va[s][j]; t.e[4 + j] = (f16)vb[s][j]; }
    *(f16x8*)(xh + (size_t)rw[s] * 320 + cc[s]) = t.v;
  }
}

#define QW_WCE 640
#define QW_BC  648
#define QW_WT  1288
#define QW_Z   4360

__global__ __launch_bounds__(256)
void prep_w(const float* __restrict__ W_emb, const float* __restrict__ b_emb,
            const float* __restrict__ wx0, const float* __restrict__ wh0,
            const float* __restrict__ b0,
            const float* __restrict__ wx1, const float* __restrict__ wh1,
            const float* __restrict__ wx2, const float* __restrict__ wh2,
            f16* __restrict__ W0T, f16* __restrict__ W1T, f16* __restrict__ W2T,
            float* __restrict__ bcomb,
            f16* __restrict__ H0a, f16* __restrict__ H1b, f16* __restrict__ H2a)
{
  __shared__ float smem[16384];   // 64 KB: Wce panels [16][512]+[512][16] / red
  const int b   = blockIdx.x;
  const int tid = threadIdx.x;
  const floatx4 z4 = {0.f, 0.f, 0.f, 0.f};

  if (b < QW_WCE) {
    // Wce[k][n] = sum_j W_emb[k][j]*wx0[j][n] -> W0T[n][512+k], f16.
    // 640 blocks = 20 k-tiles x 32 n-tiles; 256 outputs (16k x 16n) per block.
    float* wes = smem;            // [16][512]  W_emb rows k0..k0+15 (0-pad >=300)
    float* wxs = smem + 8192;     // [512][16]  wx0 cols n0..n0+15
    const int kt = b >> 5, nt = b & 31;
    const int k0 = kt * 16, n0 = nt * 16;
    const int rr = tid >> 4, cc = tid & 15;
    {
      const int k = k0 + rr;
      #pragma unroll
      for (int q = 0; q < 8; ++q) {
        floatx4 v = (k < 300) ? *(const floatx4*)&W_emb[(size_t)k * 512 + cc * 32 + q * 4] : z4;
        *(floatx4*)&wes[rr * 512 + cc * 32 + q * 4] = v;
      }
    }
    #pragma unroll 4
    for (int jj = 0; jj < 32; ++jj) {
      int j = rr * 32 + jj;
      wxs[j * 16 + cc] = wx0[(size_t)j * 512 + n0 + cc];
    }
    __syncthreads();
    float s = 0.f;
    #pragma unroll 8
    for (int j = 0; j < 512; ++j)
      s = __builtin_fmaf(wes[rr * 512 + j], wxs[j * 16 + cc], s);
    W0T[(size_t)(n0 + cc) * 832 + 512 + k0 + rr] = (f16)s;
  } else if (b < QW_BC) {
    // bcomb[n] = b0[n] + sum_j b_emb[j]*wx0[j][n]; 8 blocks, split-K x4
    float* red = smem;
    int n     = (b - QW_WCE) * 64 + (tid & 63);
    int chunk = tid >> 6;
    float s = 0.f;
    const float* be = b_emb + chunk * 128;
    const float* wx = wx0 + (size_t)(chunk * 128) * 512 + n;
    #pragma unroll 4
    for (int j = 0; j < 128; ++j)
      s = __builtin_fmaf(be[j], wx[(size_t)j * 512], s);
    red[tid] = s;
    __syncthreads();
    if (chunk == 0)
      bcomb[n] = b0[n] + red[tid] + red[tid + 64] + red[tid + 128] + red[tid + 192];
  } else if (b < QW_WT) {
    // transposes, f16x8 stores: 640*256 = 163,840 k8-chunks
    int id = (b - QW_BC) * 256 + tid;
    if (id < 32768) {                        // W0T k<512 from wh0
      int n = id & 511, k8 = id >> 9;        // k8 0..63
      union { f16 e[8]; f16x8 v; } t;
      #pragma unroll
      for (int j = 0; j < 8; ++j) t.e[j] = (f16)wh0[(size_t)(k8 * 8 + j) * 512 + n];
      *(f16x8*)&W0T[(size_t)n * 832 + k8 * 8] = t.v;
    } else if (id < 98304) {                 // W1T from wx1/wh1
      int i2 = id - 32768;
      int n = i2 & 511, k8 = i2 >> 9;        // k8 0..127; chunks don't straddle 512
      union { f16 e[8]; f16x8 v; } t;
      const float* src = (k8 < 64) ? (wx1 + (size_t)(k8 * 8) * 512 + n)
                                   : (wh1 + (size_t)((k8 - 64) * 8) * 512 + n);
      #pragma unroll
      for (int j = 0; j < 8; ++j) t.e[j] = (f16)src[(size_t)j * 512];
      *(f16x8*)&W1T[(size_t)n * 1024 + k8 * 8] = t.v;
    } else {                                 // W2T from wx2/wh2
      int i2 = id - 98304;
      int n = i2 & 511, k8 = i2 >> 9;
      union { f16 e[8]; f16x8 v; } t;
      const float* src = (k8 < 64) ? (wx2 + (size_t)(k8 * 8) * 512 + n)
                                   : (wh2 + (size_t)((k8 - 64) * 8) * 512 + n);
      #pragma unroll
      for (int j = 0; j < 8; ++j) t.e[j] = (f16)src[(size_t)j * 512];
      *(f16x8*)&W2T[(size_t)n * 1024 + k8 * 8] = t.v;
    }
  } else {
    // zero-init h(-1): H0a, H1b, H2a — 3072*256 = 786,432 f16x8 chunks
    int id = (b - QW_WT) * 256 + tid;
    f16x8 z8 = {};
    f16* dst = (id < 262144) ? H0a : (id < 524288) ? H1b : H2a;
    *(f16x8*)(dst + (size_t)(id & 262143) * 8) = z8;
  }
}

// out[4096,10] = h2[4096,512](f16) @ W_fc[512,10] + b_fc; W_fc staged in LDS
__global__ void fc_kernel(const f16* __restrict__ h2,
                          const float* __restrict__ Wfc, const float* __restrict__ bfc,
                          float* __restrict__ out)
{
  __shared__ float wf[5120];
  __shared__ float bf[16];
  const int tid = threadIdx.x;
  for (int i = tid; i < 5120; i += 256) wf[i] = Wfc[i];
  if (tid < 10) bf[tid] = bfc[tid];
  __syncthreads();
  int id = blockIdx.x * 256 + tid;           // 40960 exactly
  int row = id / 10;
  int c = id - row * 10;
  float s = bf[c];
  const f16* hr = h2 + (size_t)row * 512;
  for (int k8 = 0; k8 < 64; ++k8) {
    f16x8 h8 = *(const f16x8*)(hr + k8 * 8);
    #pragma unroll
    for (int j = 0; j < 8; ++j)
      s = __builtin_fmaf((float)h8[j], wf[(k8 * 8 + j) * 10 + c], s);
  }
  out[id] = s;
}

extern "C" void kernel_launch(void* const* d_in, const int* in_sizes, int n_in,
                              void* d_out, int out_size, void* d_ws, size_t ws_size,
                              hipStream_t stream)
{
  (void)in_sizes; (void)n_in; (void)out_size; (void)ws_size;
  const float* x     = (const float*)d_in[0];
  const float* W_emb = (const float*)d_in[1];
  const float* b_emb = (const float*)d_in[2];
  const float* wx0   = (const float*)d_in[3];
  const float* wh0   = (const float*)d_in[4];
  const float* b0    = (const float*)d_in[5];
  const float* wx1   = (const float*)d_in[6];
  const float* wh1   = (const float*)d_in[7];
  const float* b1    = (const float*)d_in[8];
  const float* wx2   = (const float*)d_in[9];
  const float* wh2   = (const float*)d_in[10];
  const float* b2    = (const float*)d_in[11];
  const float* W_fc  = (const float*)d_in[12];
  const float* b_fc  = (const float*)d_in[13];
  float* out = (float*)d_out;

  char* ws = (char*)d_ws;
  size_t off = 0;
  auto alloc = [&](size_t bytes) -> void* {
    void* p = ws + off;
    off = (off + bytes + 255) & ~(size_t)255;
    return p;
  };
  f16*   xh    = (f16*)alloc((size_t)81920 * 320 * 2);   // 52.4 MB
  f16*   W0T   = (f16*)alloc((size_t)512 * 832 * 2);
  f16*   W1T   = (f16*)alloc((size_t)512 * 1024 * 2);
  f16*   W2T   = (f16*)alloc((size_t)512 * 1024 * 2);
  float* bcomb = (float*)alloc(512 * 4);
  f16*   H0a   = (f16*)alloc((size_t)4096 * 512 * 2);
  f16*   H0b   = (f16*)alloc((size_t)4096 * 512 * 2);
  f16*   H1a   = (f16*)alloc((size_t)4096 * 512 * 2);
  f16*   H1b   = (f16*)alloc((size_t)4096 * 512 * 2);
  f16*   H2a   = (f16*)alloc((size_t)4096 * 512 * 2);
  f16*   H2b   = (f16*)alloc((size_t)4096 * 512 * 2);

  // prep: two dispatches (xh conversion | weights/bias/zero-init)
  prep_x<<<PX_N, 256, 0, stream>>>(x, xh);
  prep_w<<<QW_Z, 256, 0, stream>>>(W_emb, b_emb, wx0, wh0, b0,
                                   wx1, wh1, wx2, wh2,
                                   W0T, W1T, W2T, bcomb, H0a, H1b, H2a);

  // 22 anti-diagonal wavefronts: z0(t=wv), z1(t=wv-1), z2(t=wv-2)
  for (int wv = 0; wv < 22; ++wv) {
    const int cur = wv & 1;
    f16* H0c = cur ? H0b : H0a;  f16* H0n = cur ? H0a : H0b;
    f16* H1c = cur ? H1b : H1a;  f16* H1n = cur ? H1a : H1b;
    f16* H2c = cur ? H2b : H2a;  f16* H2n = cur ? H2a : H2b;
    rnn_step<<<512, 256, 0, stream>>>(wv, xh, W0T, W1T, W2T, bcomb, b1, b2,
                                      H0c, H0n, H1c, H1n, H2c, H2n);
  }

  // h2(19) written at wv=21 into H2n(cur=1) = H2a
  fc_kernel<<<160, 256, 0, stream>>>(H2a, W_fc, b_fc, out);
}